// Round 14
// baseline (92.483 us; speedup 1.0000x reference)
//
#include <hip/hip_runtime.h>

typedef __attribute__((ext_vector_type(4))) float f32x4;
typedef __attribute__((ext_vector_type(8))) short s16x8;

#define NG     8000
#define NRPT   8000
#define NSKIN  128
#define NT     64          // r-cols per block
#define KCH    800
#define NKC    10
#define NTILES 25          // 32-k tiles per chunk
#define NROUND 10          // 80-g staging rounds per chunk
#define NSLOT  6           // ring slots (192 g): live window <= 176 g -> disjoint
#define TPB    256
#define WS_TILE_B 16384    // per 32k-tile: Ar|Ai planes, 8KB each, fragment-ordered
#define WS_NEED   ((size_t)NKC*NTILES*WS_TILE_B)   // 4,096,000 B

__device__ __forceinline__ float sin_rev(float u){ float r; asm("v_sin_f32 %0, %1" : "=v"(r) : "v"(u)); return r; }
__device__ __forceinline__ float cos_rev(float u){ float r; asm("v_cos_f32 %0, %1" : "=v"(r) : "v"(u)); return r; }
__device__ __forceinline__ unsigned int cvt_pk(float lo, float hi){
    unsigned int r; asm("v_cvt_pk_bf16_f32 %0, %1, %2" : "=v"(r) : "v"(lo), "v"(hi)); return r;
}
__device__ __forceinline__ s16x8 bneg(s16x8 v){
    int4 u = *(int4*)&v;
    u.x ^= 0x80008000; u.y ^= 0x80008000; u.z ^= 0x80008000; u.w ^= 0x80008000;
    return *(s16x8*)&u;
}
__device__ __forceinline__ s16x8 pack8(float4 v0, float4 v1){
    union { s16x8 v; uint4 u; } r;
    r.u.x = cvt_pk(v0.x,v0.y); r.u.y = cvt_pk(v0.z,v0.w);
    r.u.z = cvt_pk(v1.x,v1.y); r.u.w = cvt_pk(v1.z,v1.w);
    return r.v;
}
// swizzled byte offset of 16B granule (row,kg) in a [64][32]-ushort plane (64B rows).
// kg' = kg ^ ((row>>1)&3): b128 writes and b128 frag reads (rows base+frow,
// kg=lane>>4) both land 8 lanes per 16B bank-group -> conflict-free.
__device__ __forceinline__ int swz(int row, int kg){
    return row*64 + ((kg ^ ((row>>1)&3))<<4);
}

// ---- pre-pass: cg fp32 -> bf16 in MFMA-fragment order ----
__global__ __launch_bounds__(256) void bloch_prepass(
    const float* __restrict__ cgr, const float* __restrict__ cgi,
    char* __restrict__ ws)
{
    int gid = blockIdx.x*256 + threadIdx.x;
    if (gid >= NKC*NTILES*2*8*64) return;
    int lane  = gid & 63;
    int rb8   = (gid >> 6) & 7;
    int plane = (gid >> 9) & 1;
    int tile  = gid >> 10;
    int row   = rb8*16 + (lane & 15);
    int k     = tile*32 + (lane >> 4)*8;
    const float* src = plane ? cgi : cgr;
    const float4 v0 = *(const float4*)&src[(size_t)row*NG + k];
    const float4 v1 = *(const float4*)&src[(size_t)row*NG + k + 4];
    uint4 p;
    p.x = cvt_pk(v0.x, v0.y); p.y = cvt_pk(v0.z, v0.w);
    p.z = cvt_pk(v1.x, v1.y); p.w = cvt_pk(v1.z, v1.w);
    *(uint4*)(ws + (size_t)gid*16) = p;
}

// (256,2): cap 256 VGPR (R8 lesson: tighter caps spill the 64-reg acc).
// acc 64 regs pins us in the 129-256 band (8 waves/CU) regardless -> spend
// registers on ILP: fully-static unroll + 2-deep A prefetch.
template<bool PRE>
__global__ __launch_bounds__(TPB, 2) void bloch13(
    const float* __restrict__ Amat, const float* __restrict__ kgrid,
    const float* __restrict__ cgr,  const float* __restrict__ cgi,
    const float* __restrict__ rpts, const char* __restrict__ ws,
    float* __restrict__ out, int out_size)
{
    // B ring: 6 slots x (Bc 4K | Bs 4K) = 48KB (192 g).
    // Disjointness (mod 192): iter R reads [floor(5R/2)*32, 80R+80),
    // writes [80R+80, 80R+160); span <= 176 < 192 -> never intersect.
    __shared__ __align__(16) char smem[NSLOT*8192];
    __shared__ float fracS[NT][4];
    __shared__ float invAS[9];
    __shared__ float scaleS;

    const int tid = threadIdx.x;
    const int bid = blockIdx.x;
    const int kc  = bid >> 7;           // 0..9
    const int rb  = bid & 127;          // 0..127
    if (rb >= 125) return;              // uniform early-out
    const int r_base = rb * NT;

    if (tid == 0) {
        float a00=Amat[0],a01=Amat[1],a02=Amat[2];
        float a10=Amat[3],a11=Amat[4],a12=Amat[5];
        float a20=Amat[6],a21=Amat[7],a22=Amat[8];
        float c00 =  (a11*a22 - a12*a21);
        float c01 = -(a10*a22 - a12*a20);
        float c02 =  (a10*a21 - a11*a20);
        float det = a00*c00 + a01*c01 + a02*c02;
        float id  = 1.0f/det;
        invAS[0] =  c00*id;
        invAS[1] = -(a01*a22 - a02*a21)*id;
        invAS[2] =  (a01*a12 - a02*a11)*id;
        invAS[3] =  c01*id;
        invAS[4] =  (a00*a22 - a02*a20)*id;
        invAS[5] = -(a00*a12 - a02*a10)*id;
        invAS[6] =  c02*id;
        invAS[7] = -(a00*a21 - a01*a20)*id;
        invAS[8] =  (a00*a11 - a01*a10)*id;
        scaleS   = rsqrtf(fabsf(det));
    }
    __syncthreads();

    if (tid < NT) {
        int rg = r_base + tid;
        float r0 = rpts[rg*3+0], r1 = rpts[rg*3+1], r2 = rpts[rg*3+2];
        fracS[tid][0] = r0*invAS[0] + r1*invAS[3] + r2*invAS[6];
        fracS[tid][1] = r0*invAS[1] + r1*invAS[4] + r2*invAS[7];
        fracS[tid][2] = r0*invAS[2] + r1*invAS[5] + r2*invAS[8];
    }
    __syncthreads();

    f32x4 accRe[4][2], accIm[4][2];
    #pragma unroll
    for (int mi = 0; mi < 4; ++mi)
        #pragma unroll
        for (int ni = 0; ni < 2; ++ni) {
            accRe[mi][ni] = (f32x4){0.f,0.f,0.f,0.f};
            accIm[mi][ni] = (f32x4){0.f,0.f,0.f,0.f};
        }

    const int lane = tid & 63;
    const int wid  = tid >> 6;     // 0..3
    const int wm   = wid >> 1;     // M half (64 rows)
    const int wn   = wid & 1;      // N half (32 cols)
    const int frow = lane & 15;
    const int kq   = lane >> 4;
    const int bOff = swz(wn*32 + frow, kq);

    // staging: row = lane, run index = wid (wave-uniform store paths)
    const float f0r = fracS[lane][0], f1r = fracS[lane][1], f2r = fracS[lane][2];
    float u1 = f2r - floorf(f2r);
    const float w1c = cos_rev(u1), w1s = sin_rev(u1);        // e^{2pi i f2}
    float yd = -20.0f * f2r; yd -= floorf(yd);
    const float wdc = cos_rev(yd), wds = sin_rev(yd);
    const float w1wdc = w1c*wdc - w1s*wds;                   // w1 * e^{-2pi i 20 f2}
    const float w1wds = w1c*wds + w1s*wdc;

    // stage round R: 20-aligned run per thread -> no boundary selects;
    // only special step is j==10 (decade jump, compile-time).
    auto stageRing = [&](int R){
        int i12 = kc*40 + 4*R + wid;             // (kc*800 + R*80 + wid*20)/20
        int i1  = (i12 * 3277) >> 16;            // /20 exact for i12<16000
        int i2  = i12 - i1*20;
        float m1 = (float)(i1 - (i1 >= 10 ? 20 : 0));
        float m2 = (float)(i2 - (i2 >= 10 ? 20 : 0));
        float y0 = m1*f0r + m2*f1r; y0 -= floorf(y0);
        float cc = cos_rev(y0), cs = sin_rev(y0);            // phase j=0 (m3=0)
        unsigned int pkc[10], pks[10];
        #pragma unroll
        for (int jj = 0; jj < 10; ++jj) {
            float ac = cc, as_ = cs;
            { float nc = cc*w1c - cs*w1s, ns = cc*w1s + cs*w1c; cc=nc; cs=ns; } // -> j=2jj+1
            pkc[jj] = cvt_pk(ac, cc);
            pks[jj] = cvt_pk(as_, cs);
            if (jj < 9) {                                    // -> j=2jj+2
                if (jj == 4) { float nc = cc*w1wdc - cs*w1wds, ns = cc*w1wds + cs*w1wdc; cc=nc; cs=ns; }
                else         { float nc = cc*w1c  - cs*w1s,  ns = cc*w1s  + cs*w1c;  cc=nc; cs=ns; }
            }
        }
        // ring g-position of run start (multiple of 4): mod 192
        int gg = (80*R + wid*20) % 192;
        int gA = gg >> 3;                        // starting granule (0..23)
        auto adr = [&](int g, int p)->char* {
            if (g >= 24) g -= 24;
            return smem + (g>>2)*8192 + p*4096 + swz(lane, g&3);
        };
        if ((gg & 7) == 0) {                     // granule-aligned start: 8,8,4
            *(uint4*)adr(gA,0)   = make_uint4(pkc[0],pkc[1],pkc[2],pkc[3]);
            *(uint4*)adr(gA+1,0) = make_uint4(pkc[4],pkc[5],pkc[6],pkc[7]);
            *(uint2*)adr(gA+2,0) = make_uint2(pkc[8],pkc[9]);
            *(uint4*)adr(gA,1)   = make_uint4(pks[0],pks[1],pks[2],pks[3]);
            *(uint4*)adr(gA+1,1) = make_uint4(pks[4],pks[5],pks[6],pks[7]);
            *(uint2*)adr(gA+2,1) = make_uint2(pks[8],pks[9]);
        } else {                                 // mid-granule start (+4 g): 4,8,8
            *(uint2*)(adr(gA,0)+8) = make_uint2(pkc[0],pkc[1]);
            *(uint4*)adr(gA+1,0)   = make_uint4(pkc[2],pkc[3],pkc[4],pkc[5]);
            *(uint4*)adr(gA+2,0)   = make_uint4(pkc[6],pkc[7],pkc[8],pkc[9]);
            *(uint2*)(adr(gA,1)+8) = make_uint2(pks[0],pks[1]);
            *(uint4*)adr(gA+1,1)   = make_uint4(pks[2],pks[3],pks[4],pks[5]);
            *(uint4*)adr(gA+2,1)   = make_uint4(pks[6],pks[7],pks[8],pks[9]);
        }
    };

    // 2-deep A double buffer; buf index is compile-time (tt&1) under full unroll
    s16x8 arf[2][4], aif[2][4];
    auto loadA = [&](int t, int b){
        if (PRE) {
            const char* tb = ws + (size_t)(kc*NTILES + t)*WS_TILE_B + lane*16;
            #pragma unroll
            for (int mi = 0; mi < 4; ++mi) {
                arf[b][mi] = *(const s16x8*)(tb +        (wm*4 + mi)*1024);
                aif[b][mi] = *(const s16x8*)(tb + 8192 + (wm*4 + mi)*1024);
            }
        } else {
            #pragma unroll
            for (int mi = 0; mi < 4; ++mi) {
                int row = wm*64 + mi*16 + frow;
                int k   = kc*KCH + t*32 + kq*8;
                const float* pr_ = &cgr[(size_t)row*NG + k];
                const float* pi_ = &cgi[(size_t)row*NG + k];
                arf[b][mi] = pack8(*(const float4*)pr_, *(const float4*)(pr_+4));
                aif[b][mi] = pack8(*(const float4*)pi_, *(const float4*)(pi_+4));
            }
        }
    };

    // prologue: A for tiles 0,1 in flight; stage round 0
    loadA(0, 0);
    loadA(1, 1);
    stageRing(0);
    __syncthreads();

    // fully-static schedule: all loop bounds, ring slots, buffer parity literal
    #pragma unroll
    for (int R = 0; R < NROUND; ++R) {
        if (R + 1 < NROUND) stageRing(R + 1);
        #pragma unroll
        for (int tt = (5*R) >> 1; tt < (5*R + 5) >> 1; ++tt) {
            const int slot = tt % NSLOT;         // literal under unroll
            const int b    = tt & 1;             // literal under unroll
            const char* base = smem + slot*8192;
            s16x8 bcf[2], bsf[2], bsnf[2];
            #pragma unroll
            for (int ni = 0; ni < 2; ++ni) {
                bcf[ni]  = *(const s16x8*)(base +        bOff + ni*1024);
                bsf[ni]  = *(const s16x8*)(base + 4096 + bOff + ni*1024);
                bsnf[ni] = bneg(bsf[ni]);
            }
            __builtin_amdgcn_s_setprio(1);
            #pragma unroll
            for (int mi = 0; mi < 4; ++mi)
                #pragma unroll
                for (int ni = 0; ni < 2; ++ni) {
                    accRe[mi][ni] = __builtin_amdgcn_mfma_f32_16x16x32_bf16(arf[b][mi], bcf[ni],  accRe[mi][ni], 0, 0, 0);
                    accRe[mi][ni] = __builtin_amdgcn_mfma_f32_16x16x32_bf16(aif[b][mi], bsnf[ni], accRe[mi][ni], 0, 0, 0);
                    accIm[mi][ni] = __builtin_amdgcn_mfma_f32_16x16x32_bf16(arf[b][mi], bsf[ni],  accIm[mi][ni], 0, 0, 0);
                    accIm[mi][ni] = __builtin_amdgcn_mfma_f32_16x16x32_bf16(aif[b][mi], bcf[ni],  accIm[mi][ni], 0, 0, 0);
                }
            __builtin_amdgcn_s_setprio(0);
            if (tt + 2 < NTILES) loadA(tt + 2, b);   // refill freed buffer; ~1 tile in flight
        }
        __syncthreads();                         // round R+1 visible; ring reuse safe
    }

    // ---- e^{i k.r} table overlay on smem; one sincos per thread ----
    float2* ekr = (float2*)smem;   // [64][4]
    {
        int col = tid >> 2, kidx = tid & 3;
        int rg = r_base + col;
        float r0 = rpts[rg*3+0], r1 = rpts[rg*3+1], r2 = rpts[rg*3+2];
        float ang = (r0*kgrid[kidx*3+0] + r1*kgrid[kidx*3+1] + r2*kgrid[kidx*3+2])
                    * 0.15915494309189535f;
        float u = ang - floorf(ang);
        ekr[col*4+kidx] = make_float2(cos_rev(u), sin_rev(u));
    }
    __syncthreads();

    // ---- epilogue: rotate by exp(i k.r), scale, atomic-accumulate ----
    const bool write_imag = (out_size >= 2*NSKIN*NRPT);
    const float scale = scaleS;
    #pragma unroll
    for (int mi = 0; mi < 4; ++mi) {
        const int m0 = wm*64 + mi*16;
        const int kidx = (m0 >> 4) & 3;
        #pragma unroll
        for (int ni = 0; ni < 2; ++ni) {
            int col = wn*32 + ni*16 + frow;
            int rg = r_base + col;
            float2 e = ekr[col*4+kidx];
            float ck = e.x, sk = e.y;
            #pragma unroll
            for (int v = 0; v < 4; ++v) {
                int sg = m0 + kq*4 + v;
                float re = accRe[mi][ni][v];
                float im = accIm[mi][ni][v];
                float orr = (re*ck - im*sk) * scale;
                size_t lin = (size_t)sg * NRPT + rg;
                if (write_imag) {
                    float oi = (re*sk + im*ck) * scale;
                    size_t idx = lin * 2;
                    if (idx + 1 < (size_t)out_size) {
                        atomicAdd(&out[idx],   orr);
                        atomicAdd(&out[idx+1], oi);
                    }
                } else {
                    atomicAdd(&out[lin], orr);
                }
            }
        }
    }
}

extern "C" void kernel_launch(void* const* d_in, const int* in_sizes, int n_in,
                              void* d_out, int out_size, void* d_ws, size_t ws_size,
                              hipStream_t stream) {
    const float* Amat  = (const float*)d_in[0];
    const float* kgrid = (const float*)d_in[1];
    const float* cgr   = (const float*)d_in[2];
    const float* cgi   = (const float*)d_in[3];
    const float* rpts  = (const float*)d_in[4];
    float* out = (float*)d_out;

    hipMemsetAsync(d_out, 0, (size_t)out_size * sizeof(float), stream);

    const bool use_pre = (ws_size >= WS_NEED);
    dim3 grid(NKC * 128);   // kc = bid>>7, rb = bid&127 (3 dead bids per kc)
    if (use_pre) {
        bloch_prepass<<<dim3(NKC*NTILES*2*8*64/256), 256, 0, stream>>>(cgr, cgi, (char*)d_ws);
        bloch13<true><<<grid, TPB, 0, stream>>>(Amat, kgrid, cgr, cgi, rpts,
                                                (const char*)d_ws, out, out_size);
    } else {
        bloch13<false><<<grid, TPB, 0, stream>>>(Amat, kgrid, cgr, cgi, rpts,
                                                 nullptr, out, out_size);
    }
}

// Round 15
// 92.022 us; speedup vs baseline: 1.0050x; 1.0050x over previous
//
#include <hip/hip_runtime.h>

typedef __attribute__((ext_vector_type(4))) float f32x4;
typedef __attribute__((ext_vector_type(8))) short s16x8;

#define NG     8000
#define NRPT   8000
#define NSKIN  128
#define NT     64          // r-cols per block
#define KCH    800
#define NKC    10
#define NTILES 25          // 32-k tiles per chunk
#define NROUND 10          // 80-g staging rounds per chunk
#define NSLOT  6           // ring slots (192 g): live window <= 176 g -> disjoint
#define TPB    256
#define WS_TILE_B 16384    // per 32k-tile: Ar|Ai planes, 8KB each, fragment-ordered
#define WS_NEED   ((size_t)NKC*NTILES*WS_TILE_B)   // 4,096,000 B

__device__ __forceinline__ float sin_rev(float u){ float r; asm("v_sin_f32 %0, %1" : "=v"(r) : "v"(u)); return r; }
__device__ __forceinline__ float cos_rev(float u){ float r; asm("v_cos_f32 %0, %1" : "=v"(r) : "v"(u)); return r; }
__device__ __forceinline__ unsigned int cvt_pk(float lo, float hi){
    unsigned int r; asm("v_cvt_pk_bf16_f32 %0, %1, %2" : "=v"(r) : "v"(lo), "v"(hi)); return r;
}
__device__ __forceinline__ s16x8 bneg(s16x8 v){
    int4 u = *(int4*)&v;
    u.x ^= 0x80008000; u.y ^= 0x80008000; u.z ^= 0x80008000; u.w ^= 0x80008000;
    return *(s16x8*)&u;
}
__device__ __forceinline__ s16x8 pack8(float4 v0, float4 v1){
    union { s16x8 v; uint4 u; } r;
    r.u.x = cvt_pk(v0.x,v0.y); r.u.y = cvt_pk(v0.z,v0.w);
    r.u.z = cvt_pk(v1.x,v1.y); r.u.w = cvt_pk(v1.z,v1.w);
    return r.v;
}
// swizzled byte offset of 16B granule (row,kg) in a [64][32]-ushort plane (64B rows).
// kg' = kg ^ ((row>>1)&3): b128 writes and b128 frag reads (rows base+frow,
// kg=lane>>4) both land 8 lanes per 16B bank-group -> conflict-free.
__device__ __forceinline__ int swz(int row, int kg){
    return row*64 + ((kg ^ ((row>>1)&3))<<4);
}

// ---- pre-pass: cg fp32 -> bf16 in MFMA-fragment order ----
__global__ __launch_bounds__(256) void bloch_prepass(
    const float* __restrict__ cgr, const float* __restrict__ cgi,
    char* __restrict__ ws)
{
    int gid = blockIdx.x*256 + threadIdx.x;
    if (gid >= NKC*NTILES*2*8*64) return;
    int lane  = gid & 63;
    int rb8   = (gid >> 6) & 7;
    int plane = (gid >> 9) & 1;
    int tile  = gid >> 10;
    int row   = rb8*16 + (lane & 15);
    int k     = tile*32 + (lane >> 4)*8;
    const float* src = plane ? cgi : cgr;
    const float4 v0 = *(const float4*)&src[(size_t)row*NG + k];
    const float4 v1 = *(const float4*)&src[(size_t)row*NG + k + 4];
    uint4 p;
    p.x = cvt_pk(v0.x, v0.y); p.y = cvt_pk(v0.z, v0.w);
    p.z = cvt_pk(v1.x, v1.y); p.w = cvt_pk(v1.z, v1.w);
    *(uint4*)(ws + (size_t)gid*16) = p;
}

// Latency-bound fix (R14 analysis): acc 64->32 regs (wave tile 64x32 -> 32x32,
// M-split across blocks) to raise residency 8 -> 12 waves/CU. (256,3): cap 170,
// expect ~104 alloc -> no spill (R8 lesson). Dynamic loop (R14: unroll cost
// occupancy). Staging/ring identical to R13 (proven correct).
template<bool PRE>
__global__ __launch_bounds__(TPB, 3) void bloch14(
    const float* __restrict__ Amat, const float* __restrict__ kgrid,
    const float* __restrict__ cgr,  const float* __restrict__ cgi,
    const float* __restrict__ rpts, const char* __restrict__ ws,
    float* __restrict__ out, int out_size)
{
    // B ring: 6 slots x (Bc 4K | Bs 4K) = 48KB (192 g).
    // Disjointness (mod 192): iter R reads [floor(5R/2)*32, 80R+80),
    // writes [80R+80, 80R+160); span <= 176 < 192 -> never intersect.
    __shared__ __align__(16) char smem[NSLOT*8192];
    __shared__ float fracS[NT][4];
    __shared__ float invAS[9];
    __shared__ float scaleS;

    const int tid = threadIdx.x;
    const int bid = blockIdx.x;
    // bid = kc*256 + rb*2 + mb: kc-partners differ by 256 -> same bid%8 -> same XCD
    const int kc  = bid >> 8;           // 0..9
    const int idx = bid & 255;
    const int rb  = idx >> 1;           // 0..127
    const int mb  = idx & 1;            // M half
    if (rb >= 125) return;              // uniform early-out
    const int r_base = rb * NT;

    if (tid == 0) {
        float a00=Amat[0],a01=Amat[1],a02=Amat[2];
        float a10=Amat[3],a11=Amat[4],a12=Amat[5];
        float a20=Amat[6],a21=Amat[7],a22=Amat[8];
        float c00 =  (a11*a22 - a12*a21);
        float c01 = -(a10*a22 - a12*a20);
        float c02 =  (a10*a21 - a11*a20);
        float det = a00*c00 + a01*c01 + a02*c02;
        float id  = 1.0f/det;
        invAS[0] =  c00*id;
        invAS[1] = -(a01*a22 - a02*a21)*id;
        invAS[2] =  (a01*a12 - a02*a11)*id;
        invAS[3] =  c01*id;
        invAS[4] =  (a00*a22 - a02*a20)*id;
        invAS[5] = -(a00*a12 - a02*a10)*id;
        invAS[6] =  c02*id;
        invAS[7] = -(a00*a21 - a01*a20)*id;
        invAS[8] =  (a00*a11 - a01*a10)*id;
        scaleS   = rsqrtf(fabsf(det));
    }
    __syncthreads();

    if (tid < NT) {
        int rg = r_base + tid;
        float r0 = rpts[rg*3+0], r1 = rpts[rg*3+1], r2 = rpts[rg*3+2];
        fracS[tid][0] = r0*invAS[0] + r1*invAS[3] + r2*invAS[6];
        fracS[tid][1] = r0*invAS[1] + r1*invAS[4] + r2*invAS[7];
        fracS[tid][2] = r0*invAS[2] + r1*invAS[5] + r2*invAS[8];
    }
    __syncthreads();

    f32x4 accRe[2][2], accIm[2][2];
    #pragma unroll
    for (int mi = 0; mi < 2; ++mi)
        #pragma unroll
        for (int ni = 0; ni < 2; ++ni) {
            accRe[mi][ni] = (f32x4){0.f,0.f,0.f,0.f};
            accIm[mi][ni] = (f32x4){0.f,0.f,0.f,0.f};
        }

    const int lane = tid & 63;
    const int wid  = tid >> 6;     // 0..3
    const int wm   = wid >> 1;     // 0..1 (M quarter within half: 32 rows)
    const int wn   = wid & 1;      // 0..1 (N half: 32 cols)
    const int frow = lane & 15;
    const int kq   = lane >> 4;
    const int bOff = swz(wn*32 + frow, kq);

    // staging: row = lane, run index = wid (wave-uniform store paths)
    const float f0r = fracS[lane][0], f1r = fracS[lane][1], f2r = fracS[lane][2];
    float u1 = f2r - floorf(f2r);
    const float w1c = cos_rev(u1), w1s = sin_rev(u1);        // e^{2pi i f2}
    float yd = -20.0f * f2r; yd -= floorf(yd);
    const float wdc = cos_rev(yd), wds = sin_rev(yd);
    const float w1wdc = w1c*wdc - w1s*wds;                   // w1 * e^{-2pi i 20 f2}
    const float w1wds = w1c*wds + w1s*wdc;

    // stage round R: 20-aligned run per thread -> no boundary selects;
    // only special step is j==10 (decade jump, compile-time).
    auto stageRing = [&](int R){
        int i12 = kc*40 + 4*R + wid;             // (kc*800 + R*80 + wid*20)/20
        int i1  = (i12 * 3277) >> 16;            // /20 exact for i12<16000
        int i2  = i12 - i1*20;
        float m1 = (float)(i1 - (i1 >= 10 ? 20 : 0));
        float m2 = (float)(i2 - (i2 >= 10 ? 20 : 0));
        float y0 = m1*f0r + m2*f1r; y0 -= floorf(y0);
        float cc = cos_rev(y0), cs = sin_rev(y0);            // phase j=0 (m3=0)
        unsigned int pkc[10], pks[10];
        #pragma unroll
        for (int jj = 0; jj < 10; ++jj) {
            float ac = cc, as_ = cs;
            { float nc = cc*w1c - cs*w1s, ns = cc*w1s + cs*w1c; cc=nc; cs=ns; } // -> j=2jj+1
            pkc[jj] = cvt_pk(ac, cc);
            pks[jj] = cvt_pk(as_, cs);
            if (jj < 9) {                                    // -> j=2jj+2
                if (jj == 4) { float nc = cc*w1wdc - cs*w1wds, ns = cc*w1wds + cs*w1wdc; cc=nc; cs=ns; }
                else         { float nc = cc*w1c  - cs*w1s,  ns = cc*w1s  + cs*w1c;  cc=nc; cs=ns; }
            }
        }
        // ring g-position of run start (multiple of 4): mod 192
        int gg = (80*R + wid*20) % 192;
        int gA = gg >> 3;                        // starting granule (0..23)
        auto adr = [&](int g, int p)->char* {
            if (g >= 24) g -= 24;
            return smem + (g>>2)*8192 + p*4096 + swz(lane, g&3);
        };
        if ((gg & 7) == 0) {                     // granule-aligned start: 8,8,4
            *(uint4*)adr(gA,0)   = make_uint4(pkc[0],pkc[1],pkc[2],pkc[3]);
            *(uint4*)adr(gA+1,0) = make_uint4(pkc[4],pkc[5],pkc[6],pkc[7]);
            *(uint2*)adr(gA+2,0) = make_uint2(pkc[8],pkc[9]);
            *(uint4*)adr(gA,1)   = make_uint4(pks[0],pks[1],pks[2],pks[3]);
            *(uint4*)adr(gA+1,1) = make_uint4(pks[4],pks[5],pks[6],pks[7]);
            *(uint2*)adr(gA+2,1) = make_uint2(pks[8],pks[9]);
        } else {                                 // mid-granule start (+4 g): 4,8,8
            *(uint2*)(adr(gA,0)+8) = make_uint2(pkc[0],pkc[1]);
            *(uint4*)adr(gA+1,0)   = make_uint4(pkc[2],pkc[3],pkc[4],pkc[5]);
            *(uint4*)adr(gA+2,0)   = make_uint4(pkc[6],pkc[7],pkc[8],pkc[9]);
            *(uint2*)(adr(gA,1)+8) = make_uint2(pks[0],pks[1]);
            *(uint4*)adr(gA+1,1)   = make_uint4(pks[2],pks[3],pks[4],pks[5]);
            *(uint4*)adr(gA+2,1)   = make_uint4(pks[6],pks[7],pks[8],pks[9]);
        }
    };

    s16x8 arfP[2], aifP[2];    // prefetched A fragments (current tile)
    auto loadA = [&](int t){
        if (PRE) {
            const char* tb = ws + (size_t)(kc*NTILES + t)*WS_TILE_B + lane*16;
            #pragma unroll
            for (int mi = 0; mi < 2; ++mi) {
                arfP[mi] = *(const s16x8*)(tb +        (mb*4 + wm*2 + mi)*1024);
                aifP[mi] = *(const s16x8*)(tb + 8192 + (mb*4 + wm*2 + mi)*1024);
            }
        } else {
            #pragma unroll
            for (int mi = 0; mi < 2; ++mi) {
                int row = mb*64 + wm*32 + mi*16 + frow;
                int k   = kc*KCH + t*32 + kq*8;
                const float* pr_ = &cgr[(size_t)row*NG + k];
                const float* pi_ = &cgi[(size_t)row*NG + k];
                arfP[mi] = pack8(*(const float4*)pr_, *(const float4*)(pr_+4));
                aifP[mi] = pack8(*(const float4*)pi_, *(const float4*)(pi_+4));
            }
        }
    };

    // prologue
    loadA(0);
    stageRing(0);
    __syncthreads();

    int tcur = 0, slot = 0;
    #pragma unroll 1
    for (int R = 0; R < NROUND; ++R) {
        if (R + 1 < NROUND) stageRing(R + 1);
        const int t_hi = (5*R + 5) >> 1;         // tiles available after round R
        #pragma unroll 1
        while (tcur < t_hi) {
            const char* base = smem + slot*8192;
            s16x8 bcf[2], bsf[2], bsnf[2];
            #pragma unroll
            for (int ni = 0; ni < 2; ++ni) {
                bcf[ni]  = *(const s16x8*)(base +        bOff + ni*1024);
                bsf[ni]  = *(const s16x8*)(base + 4096 + bOff + ni*1024);
                bsnf[ni] = bneg(bsf[ni]);
            }
            __builtin_amdgcn_s_setprio(1);
            #pragma unroll
            for (int mi = 0; mi < 2; ++mi)
                #pragma unroll
                for (int ni = 0; ni < 2; ++ni) {
                    accRe[mi][ni] = __builtin_amdgcn_mfma_f32_16x16x32_bf16(arfP[mi], bcf[ni],  accRe[mi][ni], 0, 0, 0);
                    accRe[mi][ni] = __builtin_amdgcn_mfma_f32_16x16x32_bf16(aifP[mi], bsnf[ni], accRe[mi][ni], 0, 0, 0);
                    accIm[mi][ni] = __builtin_amdgcn_mfma_f32_16x16x32_bf16(arfP[mi], bsf[ni],  accIm[mi][ni], 0, 0, 0);
                    accIm[mi][ni] = __builtin_amdgcn_mfma_f32_16x16x32_bf16(aifP[mi], bcf[ni],  accIm[mi][ni], 0, 0, 0);
                }
            __builtin_amdgcn_s_setprio(0);
            ++tcur;
            if (tcur < NTILES) loadA(tcur);      // prefetch next tile's A
            ++slot; if (slot == NSLOT) slot = 0;
        }
        __syncthreads();                         // round R+1 visible; ring reuse safe
    }

    // ---- e^{i k.r} table overlay on smem; one sincos per thread ----
    float2* ekr = (float2*)smem;   // [64][4]
    {
        int col = tid >> 2, kidx = tid & 3;
        int rg = r_base + col;
        float r0 = rpts[rg*3+0], r1 = rpts[rg*3+1], r2 = rpts[rg*3+2];
        float ang = (r0*kgrid[kidx*3+0] + r1*kgrid[kidx*3+1] + r2*kgrid[kidx*3+2])
                    * 0.15915494309189535f;
        float u = ang - floorf(ang);
        ekr[col*4+kidx] = make_float2(cos_rev(u), sin_rev(u));
    }
    __syncthreads();

    // ---- epilogue: rotate by exp(i k.r), scale, atomic-accumulate ----
    const bool write_imag = (out_size >= 2*NSKIN*NRPT);
    const float scale = scaleS;
    #pragma unroll
    for (int mi = 0; mi < 2; ++mi) {
        const int m0 = mb*64 + wm*32 + mi*16;
        const int kidx = (m0 >> 4) & 3;
        #pragma unroll
        for (int ni = 0; ni < 2; ++ni) {
            int col = wn*32 + ni*16 + frow;
            int rg = r_base + col;
            float2 e = ekr[col*4+kidx];
            float ck = e.x, sk = e.y;
            #pragma unroll
            for (int v = 0; v < 4; ++v) {
                int sg = m0 + kq*4 + v;
                float re = accRe[mi][ni][v];
                float im = accIm[mi][ni][v];
                float orr = (re*ck - im*sk) * scale;
                size_t lin = (size_t)sg * NRPT + rg;
                if (write_imag) {
                    float oi = (re*sk + im*ck) * scale;
                    size_t idx2 = lin * 2;
                    if (idx2 + 1 < (size_t)out_size) {
                        atomicAdd(&out[idx2],   orr);
                        atomicAdd(&out[idx2+1], oi);
                    }
                } else {
                    atomicAdd(&out[lin], orr);
                }
            }
        }
    }
}

extern "C" void kernel_launch(void* const* d_in, const int* in_sizes, int n_in,
                              void* d_out, int out_size, void* d_ws, size_t ws_size,
                              hipStream_t stream) {
    const float* Amat  = (const float*)d_in[0];
    const float* kgrid = (const float*)d_in[1];
    const float* cgr   = (const float*)d_in[2];
    const float* cgi   = (const float*)d_in[3];
    const float* rpts  = (const float*)d_in[4];
    float* out = (float*)d_out;

    hipMemsetAsync(d_out, 0, (size_t)out_size * sizeof(float), stream);

    const bool use_pre = (ws_size >= WS_NEED);
    dim3 grid(NKC * 256);   // kc = bid>>8; idx = bid&255 -> rb = idx>>1, mb = idx&1
    if (use_pre) {
        bloch_prepass<<<dim3(NKC*NTILES*2*8*64/256), 256, 0, stream>>>(cgr, cgi, (char*)d_ws);
        bloch14<true><<<grid, TPB, 0, stream>>>(Amat, kgrid, cgr, cgi, rpts,
                                                (const char*)d_ws, out, out_size);
    } else {
        bloch14<false><<<grid, TPB, 0, stream>>>(Amat, kgrid, cgr, cgi, rpts,
                                                 nullptr, out, out_size);
    }
}